// Round 11
// baseline (135.124 us; speedup 1.0000x reference)
//
#include <hip/hip_runtime.h>
#include <hip/hip_fp16.h>

#define Bsz 8
#define Cn  4
#define Hn  64
#define Wn  2048
#define HW  (Hn*Wn)          // 131072
#define NPIX (Bsz*HW)        // 1048576

// guard-padded S layout: 2 guard cols each side, 1 guard row top/bottom
#define PW     2052
#define PROWS  66
#define PBATCH (PW*PROWS)    // 135432
#define PTOT   (Bsz*PBATCH)  // 1083456

// Gaussian stencil exp(-(dh^2+dw^2)/(2*0.9^2)), center zeroed.
#define G1 0.53940824f
#define G2 0.29096127f
#define G4 0.08465836f
#define G5 0.04566536f

struct Half4 { __half2 lo, hi; };
struct Half8 { __half2 h[4]; };

__device__ __forceinline__ __half2 bcast_lo(__half2 v) { return __half2half2(__low2half(v)); }
__device__ __forceinline__ __half2 bcast_hi(__half2 v) { return __half2half2(__high2half(v)); }

__device__ __forceinline__ float Gw(int r, int d) {
    const float Gt[3][5] = {{G5,G2,G1,G2,G5},{G4,G1,0.f,G1,G4},{G5,G2,G1,G2,G5}};
    return Gt[r][d];
}
__device__ __forceinline__ constexpr int tap_of(int r, int d) {
    return (r == 0) ? d : (r == 1) ? ((d < 2) ? 5 + d : 4 + d) : 9 + d;
}
// select tap t (0..13) from the two packed beta vectors, broadcast to half2
__device__ __forceinline__ __half2 tapsel(const Half8& a, const Half8& bv, int t) {
    __half2 h = (t < 8) ? a.h[t >> 1] : bv.h[(t - 8) >> 1];
    return (t & 1) ? bcast_hi(h) : bcast_lo(h);
}

// ---- prep: LDS-tiled beta*mask + S0 = softmax(unary) (guards pre-zeroed) ----
__global__ __launch_bounds__(256) void crf_prep(const float* __restrict__ unary,
                                                const float* __restrict__ xyz,
                                                const float* __restrict__ mask,
                                                Half8* __restrict__ BA,
                                                Half8* __restrict__ BB,
                                                Half4* __restrict__ S0) {
    __shared__ float4 XM[6 * 68];      // (xyz, mask) halo for a 64x4 tile

    const int tid = threadIdx.x;
    const int w0 = blockIdx.x * 64;
    const int h0 = blockIdx.y * 4;
    const int b  = blockIdx.z;

    const size_t qb = (size_t)b * Cn * HW;
    const size_t xb = (size_t)b * 3 * HW;
    const size_t mb = (size_t)b * HW;

    // stage halo (zeros outside image)
#pragma unroll
    for (int k = 0; k < 2; ++k) {
        int i = tid + k * 256;
        if (i < 6 * 68) {
            int hr = i / 68, hc = i - hr * 68;
            int gh = h0 + hr - 1, gw = w0 + hc - 2;
            float4 xm = make_float4(0.f, 0.f, 0.f, 0.f);
            if (gh >= 0 && gh < Hn && gw >= 0 && gw < Wn) {
                size_t p = (size_t)gh * Wn + gw;
                xm = make_float4(xyz[xb + p], xyz[xb + p + HW],
                                 xyz[xb + p + 2 * HW], mask[mb + p]);
            }
            XM[i] = xm;
        }
    }
    __syncthreads();

    const int lw = tid & 63;          // tile-local col
    const int lr = tid >> 6;          // tile-local row (0..3)
    const int li = (lr + 1) * 68 + (lw + 2);
    const int hp = h0 + lr, wp = w0 + lw;
    const size_t pl = (size_t)hp * Wn + wp;

    // beta*mask for 14 taps (OOB taps: staged zeros -> bm*0, value irrelevant)
    const float4 xc = XM[li];
    float bm[14];
    int t = 0;
#pragma unroll
    for (int dh = -1; dh <= 1; ++dh) {
#pragma unroll
        for (int dw = -2; dw <= 2; ++dw) {
            if (dh == 0 && dw == 0) continue;
            float4 xn = XM[li + dh * 68 + dw];
            float dx = xn.x - xc.x, dy = xn.y - xc.y, dz = xn.z - xc.z;
            bm[t++] = __expf(-2222.2222f * (dx * dx + dy * dy + dz * dz)) * xn.w;
        }
    }
    Half8 a, bv;
    a.h[0]  = __floats2half2_rn(bm[0],  bm[1]);
    a.h[1]  = __floats2half2_rn(bm[2],  bm[3]);
    a.h[2]  = __floats2half2_rn(bm[4],  bm[5]);
    a.h[3]  = __floats2half2_rn(bm[6],  bm[7]);
    bv.h[0] = __floats2half2_rn(bm[8],  bm[9]);
    bv.h[1] = __floats2half2_rn(bm[10], bm[11]);
    bv.h[2] = __floats2half2_rn(bm[12], bm[13]);
    bv.h[3] = __floats2half2_rn(xc.w, 0.f);
    BA[mb + pl] = a;
    BB[mb + pl] = bv;

    // S0 = softmax(unary)
    float q0 = unary[qb + pl], q1 = unary[qb + pl + HW];
    float q2 = unary[qb + pl + 2 * HW], q3 = unary[qb + pl + 3 * HW];
    float mx = fmaxf(fmaxf(q0, q1), fmaxf(q2, q3));
    float e0 = __expf(q0 - mx), e1 = __expf(q1 - mx);
    float e2 = __expf(q2 - mx), e3 = __expf(q3 - mx);
    float inv = 1.0f / (e0 + e1 + e2 + e3);
    Half4 s; s.lo = __floats2half2_rn(e0 * inv, e1 * inv);
    s.hi = __floats2half2_rn(e2 * inv, e3 * inv);
    S0[b * PBATCH + (hp + 1) * PW + (wp + 2)] = s;
}

// ---- one CRF iteration, 2 vertical px/thread, no LDS, no barriers ----
template<bool FINAL>
__device__ __forceinline__ void finish_px(__half2 kl, __half2 kh, __half2 al, __half2 ah,
                                          float mc, size_t qb, int cc,
                                          const float* __restrict__ unary,
                                          const float* __restrict__ wa,
                                          const float* __restrict__ wsm,
                                          const float* __restrict__ cw,
                                          float* __restrict__ outp,
                                          Half4* __restrict__ Sout) {
    const float ksm[4] = {__low2float(kl), __high2float(kl), __low2float(kh), __high2float(kh)};
    const float app[4] = {__low2float(al), __high2float(al), __low2float(ah), __high2float(ah)};
    float wk[4];
#pragma unroll
    for (int c = 0; c < 4; ++c)
        wk[c] = ksm[c] * (wsm[c] + wa[c] * (app[c] * mc));
    float q[4];
#pragma unroll
    for (int o = 0; o < 4; ++o) {
        float pw = cw[o*4+0]*wk[0] + cw[o*4+1]*wk[1] + cw[o*4+2]*wk[2] + cw[o*4+3]*wk[3];
        q[o] = unary[qb + (size_t)o * HW] - pw;
    }
    if (FINAL) {
#pragma unroll
        for (int o = 0; o < 4; ++o)
            outp[qb + (size_t)o * HW] = q[o];
    } else {
        float mx = fmaxf(fmaxf(q[0], q[1]), fmaxf(q[2], q[3]));
        float e0 = __expf(q[0] - mx), e1 = __expf(q[1] - mx);
        float e2 = __expf(q[2] - mx), e3 = __expf(q[3] - mx);
        float inv = 1.0f / (e0 + e1 + e2 + e3);
        Half4 s; s.lo = __floats2half2_rn(e0 * inv, e1 * inv);
        s.hi = __floats2half2_rn(e2 * inv, e3 * inv);
        Sout[cc] = s;
    }
}

template<bool FINAL>
__global__ __launch_bounds__(256) void crf_pass(const Half4* __restrict__ Sin,
                                                Half4* __restrict__ Sout,
                                                const Half8* __restrict__ BA,
                                                const Half8* __restrict__ BB,
                                                const float* __restrict__ unary,
                                                const float* __restrict__ wa,
                                                const float* __restrict__ wsm,
                                                const float* __restrict__ cw,
                                                float* __restrict__ outp) {
    const int t  = blockIdx.x * 256 + threadIdx.x;   // < NPIX/2
    const int b  = t >> 16;                          // HW/2 = 65536 pairs/batch
    const int r2 = t & 65535;
    const int ph = r2 >> 11;                         // row-pair 0..31
    const int w  = r2 & (Wn - 1);
    const int h0p = 2 * ph;

    const size_t t0 = (size_t)b * HW + (size_t)h0p * Wn + w;
    const int cc0 = b * PBATCH + (h0p + 1) * PW + (w + 2);

    const Half8 ba0 = BA[t0],      bb0 = BB[t0];
    const Half8 ba1 = BA[t0 + Wn], bb1 = BB[t0 + Wn];

    // 4-row x 5-col tap window shared by the vertical pair
    Half4 s[4][5];
#pragma unroll
    for (int r = 0; r < 4; ++r) {
        const int base = cc0 + (r - 1) * PW;
#pragma unroll
        for (int d = 0; d < 5; ++d) s[r][d] = Sin[base + d - 2];
    }

    const __half2 z2 = __float2half2_rn(0.f);
    __half2 k0l=z2,k0h=z2,a0l=z2,a0h=z2, k1l=z2,k1h=z2,a1l=z2,a1h=z2;

#pragma unroll
    for (int r = 0; r < 4; ++r) {
#pragma unroll
        for (int d = 0; d < 5; ++d) {
            if (r <= 2 && !(r == 1 && d == 2)) {          // px0: dh = r-1
                const __half2 g2 = __float2half2_rn(Gw(r, d));
                k0l = __hfma2(g2, s[r][d].lo, k0l);
                k0h = __hfma2(g2, s[r][d].hi, k0h);
                const __half2 b2 = tapsel(ba0, bb0, tap_of(r, d));
                a0l = __hfma2(b2, s[r][d].lo, a0l);
                a0h = __hfma2(b2, s[r][d].hi, a0h);
            }
            if (r >= 1 && !(r == 2 && d == 2)) {          // px1: dh = r-2
                const __half2 g2 = __float2half2_rn(Gw(r - 1, d));
                k1l = __hfma2(g2, s[r][d].lo, k1l);
                k1h = __hfma2(g2, s[r][d].hi, k1h);
                const __half2 b2 = tapsel(ba1, bb1, tap_of(r - 1, d));
                a1l = __hfma2(b2, s[r][d].lo, a1l);
                a1h = __hfma2(b2, s[r][d].hi, a1h);
            }
        }
    }

    const size_t qb0 = (size_t)b * Cn * HW + (size_t)h0p * Wn + w;
    finish_px<FINAL>(k0l, k0h, a0l, a0h, __half2float(__low2half(bb0.h[3])),
                     qb0, cc0, unary, wa, wsm, cw, outp, Sout);
    finish_px<FINAL>(k1l, k1h, a1l, a1h, __half2float(__low2half(bb1.h[3])),
                     qb0 + Wn, cc0 + PW, unary, wa, wsm, cw, outp, Sout);
}

extern "C" void kernel_launch(void* const* d_in, const int* in_sizes, int n_in,
                              void* d_out, int out_size, void* d_ws, size_t ws_size,
                              hipStream_t stream) {
    const float* unary  = (const float*)d_in[0];
    const float* xyz    = (const float*)d_in[1];
    const float* mask   = (const float*)d_in[2];
    const float* wa     = (const float*)d_in[3];
    const float* wsm    = (const float*)d_in[4];
    const float* compat = (const float*)d_in[5];
    float* outp = (float*)d_out;

    char* ws = (char*)d_ws;                          // 256 MB
    Half8* BA = (Half8*)ws;                          // 16 MiB
    Half8* BB = (Half8*)(ws + (size_t)NPIX * 16);    // 16 MiB
    Half4* S0 = (Half4*)(ws + (size_t)NPIX * 32);    // padded, 8.67 MiB
    Half4* S1 = (Half4*)(ws + (size_t)NPIX * 32 + (size_t)PTOT * 8);

    // zero both padded S buffers (guard ring must be 0; interiors overwritten)
    hipMemsetAsync(S0, 0, (size_t)PTOT * 8 * 2, stream);

    dim3 blk(256);
    crf_prep<<<dim3(Wn / 64, Hn / 4, Bsz), blk, 0, stream>>>(unary, xyz, mask, BA, BB, S0);
    dim3 pgrid(NPIX / 2 / 256);
    crf_pass<false><<<pgrid, blk, 0, stream>>>(S0, S1, BA, BB, unary, wa, wsm, compat, nullptr);
    crf_pass<false><<<pgrid, blk, 0, stream>>>(S1, S0, BA, BB, unary, wa, wsm, compat, nullptr);
    crf_pass<true ><<<pgrid, blk, 0, stream>>>(S0, nullptr, BA, BB, unary, wa, wsm, compat, outp);
}